// Round 9
// baseline (338.967 us; speedup 1.0000x reference)
//
#include <hip/hip_runtime.h>
#include <math.h>

#define NN 10000
#define NE 160000
#define IN_DIM 256
#define HID_DIM 512
#define OUT_DIM 256

typedef unsigned short u16;
typedef __attribute__((ext_vector_type(8))) short bf16x8;
typedef __attribute__((ext_vector_type(4))) float f32x4;

// ---------------- bf16 split helpers ----------------

static __device__ __forceinline__ u16 f2bf(float f) {
    union { float f; unsigned u; } v; v.f = f;
    unsigned r = v.u + 0x7fffu + ((v.u >> 16) & 1u);  // RNE
    return (u16)(r >> 16);
}
static __device__ __forceinline__ float bf2f(u16 h) {
    union { unsigned u; float f; } v; v.u = ((unsigned)h) << 16;
    return v.f;
}

// ---------------- fused init: weight transpose/split + deg zero ----------------

__global__ void k_init(const float* __restrict__ W1, const float* __restrict__ W2,
                       const float* __restrict__ W3,
                       u16* __restrict__ W1h, u16* __restrict__ W1l,
                       u16* __restrict__ W2h, u16* __restrict__ W2l,
                       u16* __restrict__ W3h, u16* __restrict__ W3l,
                       int* __restrict__ deg) {
    int idx = blockIdx.x * blockDim.x + threadIdx.x;
    const int S1 = IN_DIM * HID_DIM;
    const int S2 = HID_DIM * HID_DIM;
    const int S3 = HID_DIM * OUT_DIM;
    const int TW = S1 + S2 + S3;
    if (idx < TW) {
        const float* W; u16 *Th, *Tl; int K, N, local;
        if (idx < S1)           { W = W1; Th = W1h; Tl = W1l; K = IN_DIM;  N = HID_DIM; local = idx; }
        else if (idx < S1 + S2) { W = W2; Th = W2h; Tl = W2l; K = HID_DIM; N = HID_DIM; local = idx - S1; }
        else                    { W = W3; Th = W3h; Tl = W3l; K = HID_DIM; N = OUT_DIM; local = idx - S1 - S2; }
        int k = local / N, n = local - k * N;
        float v = W[local];
        u16 h = f2bf(v);
        Th[(size_t)n * K + k] = h;
        Tl[(size_t)n * K + k] = f2bf(v - bf2f(h));
    } else if (idx < TW + NN) {
        deg[idx - TW] = 0;
    }
}

// ---------------- degree / CSR build (self-loops included) ----------------

__global__ void k_count_deg(const int* __restrict__ dst, int* __restrict__ deg) {
    int e = blockIdx.x * blockDim.x + threadIdx.x;
    if (e < NE) atomicAdd(&deg[dst[e]], 1);
}

__launch_bounds__(1024)
__global__ void k_scan(const int* __restrict__ deg, int* __restrict__ row,
                       int* __restrict__ csr, float* __restrict__ dinv) {
    __shared__ int sdeg[10240];
    __shared__ int sums[1024];
    const int tid = threadIdx.x;
    for (int i = tid; i < NN; i += 1024) sdeg[i] = deg[i];
    __syncthreads();
    const int CH = 10;
    int base = tid * CH;
    int s = 0;
    for (int j = 0; j < CH; ++j) {
        int i = base + j;
        if (i < NN) s += sdeg[i] + 1;
    }
    sums[tid] = s;
    __syncthreads();
    for (int off = 1; off < 1024; off <<= 1) {
        int t = (tid >= off) ? sums[tid - off] : 0;
        __syncthreads();
        sums[tid] += t;
        __syncthreads();
    }
    int run = sums[tid] - s;
    for (int j = 0; j < CH; ++j) {
        int i = base + j;
        if (i < NN) {
            int dg = sdeg[i];
            csr[run] = i;        // self entry at slot 0
            row[i] = run + 1;    // fill cursor
            dinv[i] = rsqrtf((float)dg + 1.0f);
            run += dg + 1;
        }
    }
}

__global__ void k_fill(const int* __restrict__ src, const int* __restrict__ dst,
                       int* __restrict__ row, int* __restrict__ csr) {
    int e = blockIdx.x * blockDim.x + threadIdx.x;
    if (e < NE) {
        int pos = atomicAdd(&row[dst[e]], 1);
        csr[pos] = src[e];
    }
}

// ---------------- bf16x3 split MFMA GEMM — DIRECT-FRAGMENT, NO LDS, NO BARRIER ----
// C[M,N] = A[M,K] @ B[K,N]; A hi/lo bf16 [M][K]; B hi/lo bf16 transposed [N][K].
// MFMA fragment rows are 16B-contiguous in row-major storage -> load fragments
// straight from global (L2-resident via XCD-pinned m-slices). Zero __syncthreads
// => compiler is free to software-pipeline loads across the (fully unrolled)
// K-loop with partial vmcnt waits — the pattern the 2-barrier LDS loop forbids.
// OOB A-rows (m>=M) read in-allocation garbage; MFMA is row-independent and
// those acc rows are never stored, so it's benign.

template<int K, bool HAS_BIAS, bool DO_TANH, bool PAIR_OUT, bool ROWSCALE>
__launch_bounds__(256, 3)
__global__ void k_gemm_bf16x3(const u16* __restrict__ Ahi, const u16* __restrict__ Alo,
                              const u16* __restrict__ Bhi, const u16* __restrict__ Blo,
                              const float* __restrict__ bias, const float* __restrict__ rowscale,
                              float* __restrict__ C, u16* __restrict__ Chi, u16* __restrict__ Clo,
                              int M, int N, int MT, int MT8) {
    const int id = blockIdx.x;
    const int xcd = id & 7;
    const int q2 = id >> 3;
    const int mt = (q2 % MT8) * 8 + xcd;
    const int nt = q2 / MT8;
    if (mt >= MT) return;

    const int tid  = threadIdx.x;
    const int wave = tid >> 6;
    const int lane = tid & 63;
    const int lr   = lane & 15;
    const int quad = lane >> 4;
    const int m_base = mt * 128;
    const int n_base = nt * 64;

    const size_t arow = (size_t)(m_base + wave * 32 + lr);
    const u16* pAh = Ahi + arow * K + quad * 8;
    const u16* pAl = Alo + arow * K + quad * 8;
    const size_t brow = (size_t)(n_base + lr);
    const u16* pBh = Bhi + brow * K + quad * 8;
    const u16* pBl = Blo + brow * K + quad * 8;

    f32x4 acc[2][4] = {};

#pragma unroll
    for (int k0 = 0; k0 < K; k0 += 32) {
        bf16x8 aH[2], aL[2], bH[4], bL[4];
#pragma unroll
        for (int tm = 0; tm < 2; ++tm) {
            aH[tm] = *(const bf16x8*)(pAh + (size_t)tm * 16 * K + k0);
            aL[tm] = *(const bf16x8*)(pAl + (size_t)tm * 16 * K + k0);
        }
#pragma unroll
        for (int tn = 0; tn < 4; ++tn) {
            bH[tn] = *(const bf16x8*)(pBh + (size_t)tn * 16 * K + k0);
            bL[tn] = *(const bf16x8*)(pBl + (size_t)tn * 16 * K + k0);
        }
#pragma unroll
        for (int tm = 0; tm < 2; ++tm)
#pragma unroll
            for (int tn = 0; tn < 4; ++tn) {
                acc[tm][tn] = __builtin_amdgcn_mfma_f32_16x16x32_bf16(aH[tm], bH[tn], acc[tm][tn], 0, 0, 0);
                acc[tm][tn] = __builtin_amdgcn_mfma_f32_16x16x32_bf16(aH[tm], bL[tn], acc[tm][tn], 0, 0, 0);
                acc[tm][tn] = __builtin_amdgcn_mfma_f32_16x16x32_bf16(aL[tm], bH[tn], acc[tm][tn], 0, 0, 0);
            }
    }

    // epilogue: C/D layout col=lane&15, row=quad*4+i
#pragma unroll
    for (int tm = 0; tm < 2; ++tm) {
        int row0 = m_base + wave * 32 + tm * 16 + quad * 4;
#pragma unroll
        for (int i = 0; i < 4; ++i) {
            int row = row0 + i;
            if (row >= M) continue;
            float rs = ROWSCALE ? rowscale[row] : 1.0f;
#pragma unroll
            for (int tn = 0; tn < 4; ++tn) {
                int col = n_base + tn * 16 + lr;
                float v = acc[tm][tn][i];
                if (HAS_BIAS) v += bias[col];
                if (DO_TANH) v = tanhf(v);
                if (ROWSCALE) v *= rs;
                if (PAIR_OUT) {
                    u16 h = f2bf(v);
                    Chi[(size_t)row * N + col] = h;
                    Clo[(size_t)row * N + col] = f2bf(v - bf2f(h));
                } else {
                    C[(size_t)row * N + col] = v;
                }
            }
        }
    }
}

// ---------------- XCD-sliced fused gather aggregation ----------------

template<bool PRESCALED, bool HAS_BIAS, bool PAIR_OUT, int F4>
__launch_bounds__(256)
__global__ void k_gather(const float* __restrict__ h, const float* __restrict__ dinv,
                         const int* __restrict__ row_end, const int* __restrict__ csr,
                         const float* __restrict__ bias,
                         float* __restrict__ outF, u16* __restrict__ outH, u16* __restrict__ outL) {
    constexpr int NS = 8;
    constexpr int F4S = F4 / NS;
    constexpr int NPB = 256 / F4S;
    const int slice = blockIdx.x & (NS - 1);
    const int g = blockIdx.x >> 3;
    const int tid = threadIdx.x;
    const int d = g * NPB + tid / F4S;
    if (d >= NN) return;
    const int f = slice * F4S + (tid & (F4S - 1));

    const int start = (d == 0) ? 0 : row_end[d - 1];
    const int end = row_end[d];
    const float4* h4 = (const float4*)h;

    float ax = 0.f, ay = 0.f, az = 0.f, aw = 0.f;
    int e = start;
    for (; e + 8 <= end; e += 8) {
        int s[8]; float4 v[8]; float w[8];
#pragma unroll
        for (int j = 0; j < 8; ++j) s[j] = csr[e + j];
#pragma unroll
        for (int j = 0; j < 8; ++j) v[j] = h4[(size_t)s[j] * F4 + f];
#pragma unroll
        for (int j = 0; j < 8; ++j) w[j] = PRESCALED ? 1.0f : dinv[s[j]];
#pragma unroll
        for (int j = 0; j < 8; ++j) {
            ax += w[j] * v[j].x; ay += w[j] * v[j].y;
            az += w[j] * v[j].z; aw += w[j] * v[j].w;
        }
    }
    for (; e < end; ++e) {
        int s = csr[e];
        float w = PRESCALED ? 1.0f : dinv[s];
        float4 v = h4[(size_t)s * F4 + f];
        ax += w * v.x; ay += w * v.y; az += w * v.z; aw += w * v.w;
    }

    const float dd = dinv[d];
    float rx = dd * ax, ry = dd * ay, rz = dd * az, rw = dd * aw;
    if (HAS_BIAS) {
        float4 bv = ((const float4*)bias)[f];
        rx += bv.x; ry += bv.y; rz += bv.z; rw += bv.w;
    }
    if (PAIR_OUT) {
        u16 hx = f2bf(rx), hy = f2bf(ry), hz = f2bf(rz), hw = f2bf(rw);
        ushort4 vh = make_ushort4(hx, hy, hz, hw);
        ushort4 vl = make_ushort4(f2bf(rx - bf2f(hx)), f2bf(ry - bf2f(hy)),
                                  f2bf(rz - bf2f(hz)), f2bf(rw - bf2f(hw)));
        ((ushort4*)outH)[(size_t)d * F4 + f] = vh;
        ((ushort4*)outL)[(size_t)d * F4 + f] = vl;
    } else {
        ((float4*)outF)[(size_t)d * F4 + f] = make_float4(rx, ry, rz, rw);
    }
}

// ---------------- launch ----------------

extern "C" void kernel_launch(void* const* d_in, const int* in_sizes, int n_in,
                              void* d_out, int out_size, void* d_ws, size_t ws_size,
                              hipStream_t stream) {
    const float* x  = (const float*)d_in[0];
    const float* W1 = (const float*)d_in[1];
    const float* b1 = (const float*)d_in[2];
    const float* W2 = (const float*)d_in[3];
    const float* b2 = (const float*)d_in[4];
    const float* W3 = (const float*)d_in[5];
    const float* b3 = (const float*)d_in[6];
    const int* edge = (const int*)d_in[7];
    const int* src = edge;
    const int* dst = edge + NE;
    float* out = (float*)d_out;

    const size_t SLOT = (size_t)NN * HID_DIM * 4;
    char* p = (char*)d_ws;
    char* slot0 = p;
    char* slot1 = p + SLOT;
    char* q = p + 2 * SLOT;
    u16* W1Th = (u16*)q; q += (size_t)IN_DIM  * HID_DIM * 2;
    u16* W1Tl = (u16*)q; q += (size_t)IN_DIM  * HID_DIM * 2;
    u16* W2Th = (u16*)q; q += (size_t)HID_DIM * HID_DIM * 2;
    u16* W2Tl = (u16*)q; q += (size_t)HID_DIM * HID_DIM * 2;
    u16* W3Th = (u16*)q; q += (size_t)HID_DIM * OUT_DIM * 2;
    u16* W3Tl = (u16*)q; q += (size_t)HID_DIM * OUT_DIM * 2;
    int*   deg  = (int*)q;   q += (size_t)NN * 4;
    float* dinv = (float*)q; q += (size_t)NN * 4;
    int*   row  = (int*)q;   q += (size_t)NN * 4;
    int*   csr  = (int*)q;   q += (size_t)(NE + NN) * 4;

    u16* Xagg_h = (u16*)slot0;
    u16* Xagg_l = Xagg_h + (size_t)NN * IN_DIM;
    float* g1   = (float*)slot1;
    u16* H1h    = (u16*)slot0;
    u16* H1l    = H1h + (size_t)NN * HID_DIM;
    u16* h2h    = (u16*)slot1;
    u16* h2l    = h2h + (size_t)NN * HID_DIM;
    float* g3   = (float*)slot0;

    const int T = 256;
    const int MT = (NN + 127) / 128;   // 79
    const int MT8 = (MT + 7) / 8;      // 10

    // ---- init (wsplit + deg zero) + CSR build ----
    {
        int total = IN_DIM * HID_DIM + HID_DIM * HID_DIM + HID_DIM * OUT_DIM + NN;
        k_init<<<(total + T - 1) / T, T, 0, stream>>>(W1, W2, W3, W1Th, W1Tl,
                                                      W2Th, W2Tl, W3Th, W3Tl, deg);
    }
    k_count_deg<<<(NE + T - 1) / T, T, 0, stream>>>(dst, deg);
    k_scan<<<1, 1024, 0, stream>>>(deg, row, csr, dinv);
    k_fill<<<(NE + T - 1) / T, T, 0, stream>>>(src, dst, row, csr);

    const int G256 = ((NN + 31) / 32) * 8;
    const int G512 = ((NN + 15) / 16) * 8;
    const int GEMM_G512 = 8 * MT8 * (HID_DIM / 64);  // 640
    const int GEMM_G256 = 8 * MT8 * (OUT_DIM / 64);  // 320

    // ---- layer 1: Xagg = S*x (pair); g1 = tanh(Xagg@W1+b1)*dinv (f32) ----
    k_gather<false, false, true, IN_DIM / 4><<<G256, 256, 0, stream>>>(
        x, dinv, row, csr, nullptr, nullptr, Xagg_h, Xagg_l);
    k_gemm_bf16x3<IN_DIM, true, true, false, true><<<GEMM_G512, 256, 0, stream>>>(
        Xagg_h, Xagg_l, W1Th, W1Tl, b1, dinv, g1, nullptr, nullptr, NN, HID_DIM, MT, MT8);

    // ---- layer 2: H1agg = S*g1 (pure sum, pair); h2 = tanh(H1agg@W2+b2) (pair) ----
    k_gather<true, false, true, HID_DIM / 4><<<G512, 256, 0, stream>>>(
        g1, dinv, row, csr, nullptr, nullptr, H1h, H1l);
    k_gemm_bf16x3<HID_DIM, true, true, true, false><<<GEMM_G512, 256, 0, stream>>>(
        H1h, H1l, W2Th, W2Tl, b2, nullptr, nullptr, h2h, h2l, NN, HID_DIM, MT, MT8);

    // ---- layer 3: g3 = (h2@W3)*dinv (f32); out = S*g3 + b3 ----
    k_gemm_bf16x3<HID_DIM, false, false, false, true><<<GEMM_G256, 256, 0, stream>>>(
        h2h, h2l, W3Th, W3Tl, nullptr, dinv, g3, nullptr, nullptr, NN, OUT_DIM, MT, MT8);
    k_gather<true, true, false, OUT_DIM / 4><<<G256, 256, 0, stream>>>(
        g3, dinv, row, csr, b3, out, nullptr, nullptr);

    (void)in_sizes; (void)n_in; (void)out_size; (void)ws_size;
}

// Round 10
// 236.202 us; speedup vs baseline: 1.4351x; 1.4351x over previous
//
#include <hip/hip_runtime.h>
#include <math.h>

#define NN 10000
#define NE 160000
#define IN_DIM 256
#define HID_DIM 512
#define OUT_DIM 256

typedef unsigned short u16;
typedef _Float16 f16x8 __attribute__((ext_vector_type(8)));
typedef __attribute__((ext_vector_type(4))) float f32x4;

// ---------------- f16 helpers ----------------

union F16U { _Float16 h; u16 u; };
static __device__ __forceinline__ u16 f2h_bits(float f) {
    F16U v; v.h = (_Float16)f; return v.u;
}
static __device__ __forceinline__ float h2f(u16 b) {
    F16U v; v.u = b; return (float)v.h;
}

// ---------------- fused init: weight transpose/split + deg zero ----------------
// W[K][N] f32 -> T_hi[N][K] f16, T_lo[N][K] f16 scaled by 2048 (denormal-proof).

__global__ void k_init(const float* __restrict__ W1, const float* __restrict__ W2,
                       const float* __restrict__ W3,
                       u16* __restrict__ W1h, u16* __restrict__ W1l,
                       u16* __restrict__ W2h, u16* __restrict__ W2l,
                       u16* __restrict__ W3h, u16* __restrict__ W3l,
                       int* __restrict__ deg) {
    int idx = blockIdx.x * blockDim.x + threadIdx.x;
    const int S1 = IN_DIM * HID_DIM;
    const int S2 = HID_DIM * HID_DIM;
    const int S3 = HID_DIM * OUT_DIM;
    const int TW = S1 + S2 + S3;
    if (idx < TW) {
        const float* W; u16 *Th, *Tl; int K, N, local;
        if (idx < S1)           { W = W1; Th = W1h; Tl = W1l; K = IN_DIM;  N = HID_DIM; local = idx; }
        else if (idx < S1 + S2) { W = W2; Th = W2h; Tl = W2l; K = HID_DIM; N = HID_DIM; local = idx - S1; }
        else                    { W = W3; Th = W3h; Tl = W3l; K = HID_DIM; N = OUT_DIM; local = idx - S1 - S2; }
        int k = local / N, n = local - k * N;
        float v = W[local];
        F16U hh; hh.h = (_Float16)v;
        float r = (v - (float)hh.h) * 2048.0f;
        Th[(size_t)n * K + k] = hh.u;
        Tl[(size_t)n * K + k] = f2h_bits(r);
    } else if (idx < TW + NN) {
        deg[idx - TW] = 0;
    }
}

// ---------------- degree / CSR build (self-loops included) ----------------

__global__ void k_count_deg(const int* __restrict__ dst, int* __restrict__ deg) {
    int e = blockIdx.x * blockDim.x + threadIdx.x;
    if (e < NE) atomicAdd(&deg[dst[e]], 1);
}

__launch_bounds__(1024)
__global__ void k_scan(const int* __restrict__ deg, int* __restrict__ row,
                       int* __restrict__ csr, float* __restrict__ dinv) {
    __shared__ int sdeg[10240];
    __shared__ int sums[1024];
    const int tid = threadIdx.x;
    for (int i = tid; i < NN; i += 1024) sdeg[i] = deg[i];
    __syncthreads();
    const int CH = 10;
    int base = tid * CH;
    int s = 0;
    for (int j = 0; j < CH; ++j) {
        int i = base + j;
        if (i < NN) s += sdeg[i] + 1;
    }
    sums[tid] = s;
    __syncthreads();
    for (int off = 1; off < 1024; off <<= 1) {
        int t = (tid >= off) ? sums[tid - off] : 0;
        __syncthreads();
        sums[tid] += t;
        __syncthreads();
    }
    int run = sums[tid] - s;
    for (int j = 0; j < CH; ++j) {
        int i = base + j;
        if (i < NN) {
            int dg = sdeg[i];
            csr[run] = i;        // self entry at slot 0
            row[i] = run + 1;    // fill cursor
            dinv[i] = rsqrtf((float)dg + 1.0f);
            run += dg + 1;
        }
    }
}

__global__ void k_fill(const int* __restrict__ src, const int* __restrict__ dst,
                       int* __restrict__ row, int* __restrict__ csr) {
    int e = blockIdx.x * blockDim.x + threadIdx.x;
    if (e < NE) {
        int pos = atomicAdd(&row[dst[e]], 1);
        csr[pos] = src[e];
    }
}

// ---------------- f16 one-sided-split MFMA GEMM ----------------
// C[M,N] = A[M,K] @ B[K,N]; A single f16 [M][K]; B f16 hi + scaled-lo [N][K].
// acc = A*Bh (accH) + A*(Blo*2048) (accL); result = accH + accL/2048.
// R7-proven structure: XCD-pinned m-slices, coalesced staging -> fragment-order
// LDS chunks, double-buffered LDS, depth-1 VGPR prefetch, one barrier/iter.

struct PfSet { uint4 a0, a1, bh, bl; };

template<int K, bool HAS_BIAS, bool DO_TANH, bool F16_OUT, bool ROWSCALE>
__launch_bounds__(256)
__global__ void k_gemm_f16x2(const u16* __restrict__ A, const u16* __restrict__ Bhi,
                             const u16* __restrict__ Blo,
                             const float* __restrict__ bias, const float* __restrict__ rowscale,
                             float* __restrict__ C, u16* __restrict__ Ch,
                             int M, int N, int MT, int MT8) {
    __shared__ uint4 As[2][512];   // 128 rows x 4 kq; chunk=(row>>4)*64+kq*16+(row&15)
    __shared__ uint4 BsH[2][256];  // 64 rows x 4 kq
    __shared__ uint4 BsL[2][256];

    const int id = blockIdx.x;
    const int xcd = id & 7;
    const int q2 = id >> 3;
    const int mt = (q2 % MT8) * 8 + xcd;
    const int nt = q2 / MT8;
    if (mt >= MT) return;

    const int tid  = threadIdx.x;
    const int wave = tid >> 6;
    const int lane = tid & 63;
    const int lr   = lane & 15;
    const int quad = lane >> 4;
    const int m_base = mt * 128;
    const int n_base = nt * 64;

    const int s_row = tid >> 2;
    const int s_kq  = tid & 3;
    const int c_lo  = ((s_row >> 4) << 6) + s_kq * 16 + (s_row & 15);

    const u16* pA0 = A   + (size_t)(m_base + s_row) * K + s_kq * 8;
    const u16* pA1 = pA0 + (size_t)64 * K;
    const u16* pBh = Bhi + (size_t)(n_base + s_row) * K + s_kq * 8;
    const u16* pBl = Blo + (size_t)(n_base + s_row) * K + s_kq * 8;
    const bool g0 = (m_base + s_row) < M;
    const bool g1 = (m_base + s_row + 64) < M;

    const uint4 z = make_uint4(0u, 0u, 0u, 0u);

    auto load_set = [&](int it, PfSet& r) {
        const int ko = it * 32;
        r.a0 = z; r.a1 = z;
        if (g0) r.a0 = *(const uint4*)(pA0 + ko);
        if (g1) r.a1 = *(const uint4*)(pA1 + ko);
        r.bh = *(const uint4*)(pBh + ko);
        r.bl = *(const uint4*)(pBl + ko);
    };
    auto lds_write = [&](int buf, const PfSet& r) {
        As[buf][c_lo] = r.a0;
        As[buf][c_lo + 256] = r.a1;
        BsH[buf][c_lo] = r.bh;
        BsL[buf][c_lo] = r.bl;
    };

    f32x4 accH[2][4] = {};
    f32x4 accL[2][4] = {};

    auto compute = [&](int buf) {
        f16x8 a[2], bH[4], bL[4];
#pragma unroll
        for (int tm = 0; tm < 2; ++tm) {
            int c = (wave * 2 + tm) * 64 + lane;
            a[tm] = *(const f16x8*)&As[buf][c];
        }
#pragma unroll
        for (int tn = 0; tn < 4; ++tn) {
            int c = tn * 64 + lane;
            bH[tn] = *(const f16x8*)&BsH[buf][c];
            bL[tn] = *(const f16x8*)&BsL[buf][c];
        }
#pragma unroll
        for (int tm = 0; tm < 2; ++tm)
#pragma unroll
            for (int tn = 0; tn < 4; ++tn) {
                accH[tm][tn] = __builtin_amdgcn_mfma_f32_16x16x32_f16(a[tm], bH[tn], accH[tm][tn], 0, 0, 0);
                accL[tm][tn] = __builtin_amdgcn_mfma_f32_16x16x32_f16(a[tm], bL[tn], accL[tm][tn], 0, 0, 0);
            }
    };

    const int NIT = K >> 5;
    PfSet sA;

    load_set(0, sA);
    lds_write(0, sA);
    __syncthreads();

    for (int it = 0; it < NIT; ++it) {
        const bool has_next = (it + 1) < NIT;
        PfSet sN;
        if (has_next) load_set(it + 1, sN);
        compute(it & 1);
        if (has_next) lds_write((it + 1) & 1, sN);
        __syncthreads();
    }

    // epilogue: C/D layout col=lane&15, row=quad*4+i
#pragma unroll
    for (int tm = 0; tm < 2; ++tm) {
        int row0 = m_base + wave * 32 + tm * 16 + quad * 4;
#pragma unroll
        for (int i = 0; i < 4; ++i) {
            int row = row0 + i;
            if (row >= M) continue;
            float rs = ROWSCALE ? rowscale[row] : 1.0f;
#pragma unroll
            for (int tn = 0; tn < 4; ++tn) {
                int col = n_base + tn * 16 + lr;
                float v = accH[tm][tn][i] + accL[tm][tn][i] * (1.0f / 2048.0f);
                if (HAS_BIAS) v += bias[col];
                if (DO_TANH) v = tanhf(v);
                if (ROWSCALE) v *= rs;
                if (F16_OUT) {
                    Ch[(size_t)row * N + col] = f2h_bits(v);
                } else {
                    C[(size_t)row * N + col] = v;
                }
            }
        }
    }
}

// ---------------- XCD-sliced fused gather aggregation ----------------
// res[d] = dd * sum_{s in csr(d)} w(s)*h[s] (+bias); self-loop in csr.
// F16_OUT writes single f16 (GEMM A operand); else f32.

template<bool PRESCALED, bool HAS_BIAS, bool F16_OUT, int F4>
__launch_bounds__(256)
__global__ void k_gather(const float* __restrict__ h, const float* __restrict__ dinv,
                         const int* __restrict__ row_end, const int* __restrict__ csr,
                         const float* __restrict__ bias,
                         float* __restrict__ outF, u16* __restrict__ outH) {
    constexpr int NS = 8;
    constexpr int F4S = F4 / NS;
    constexpr int NPB = 256 / F4S;
    const int slice = blockIdx.x & (NS - 1);
    const int g = blockIdx.x >> 3;
    const int tid = threadIdx.x;
    const int d = g * NPB + tid / F4S;
    if (d >= NN) return;
    const int f = slice * F4S + (tid & (F4S - 1));

    const int start = (d == 0) ? 0 : row_end[d - 1];
    const int end = row_end[d];
    const float4* h4 = (const float4*)h;

    float ax = 0.f, ay = 0.f, az = 0.f, aw = 0.f;
    int e = start;
    for (; e + 8 <= end; e += 8) {
        int s[8]; float4 v[8]; float w[8];
#pragma unroll
        for (int j = 0; j < 8; ++j) s[j] = csr[e + j];
#pragma unroll
        for (int j = 0; j < 8; ++j) v[j] = h4[(size_t)s[j] * F4 + f];
#pragma unroll
        for (int j = 0; j < 8; ++j) w[j] = PRESCALED ? 1.0f : dinv[s[j]];
#pragma unroll
        for (int j = 0; j < 8; ++j) {
            ax += w[j] * v[j].x; ay += w[j] * v[j].y;
            az += w[j] * v[j].z; aw += w[j] * v[j].w;
        }
    }
    for (; e < end; ++e) {
        int s = csr[e];
        float w = PRESCALED ? 1.0f : dinv[s];
        float4 v = h4[(size_t)s * F4 + f];
        ax += w * v.x; ay += w * v.y; az += w * v.z; aw += w * v.w;
    }

    const float dd = dinv[d];
    float rx = dd * ax, ry = dd * ay, rz = dd * az, rw = dd * aw;
    if (HAS_BIAS) {
        float4 bv = ((const float4*)bias)[f];
        rx += bv.x; ry += bv.y; rz += bv.z; rw += bv.w;
    }
    if (F16_OUT) {
        ushort4 vh = make_ushort4(f2h_bits(rx), f2h_bits(ry), f2h_bits(rz), f2h_bits(rw));
        ((ushort4*)outH)[(size_t)d * F4 + f] = vh;
    } else {
        ((float4*)outF)[(size_t)d * F4 + f] = make_float4(rx, ry, rz, rw);
    }
}

// ---------------- launch ----------------

extern "C" void kernel_launch(void* const* d_in, const int* in_sizes, int n_in,
                              void* d_out, int out_size, void* d_ws, size_t ws_size,
                              hipStream_t stream) {
    const float* x  = (const float*)d_in[0];
    const float* W1 = (const float*)d_in[1];
    const float* b1 = (const float*)d_in[2];
    const float* W2 = (const float*)d_in[3];
    const float* b2 = (const float*)d_in[4];
    const float* W3 = (const float*)d_in[5];
    const float* b3 = (const float*)d_in[6];
    const int* edge = (const int*)d_in[7];
    const int* src = edge;
    const int* dst = edge + NE;
    float* out = (float*)d_out;

    const size_t SLOT = (size_t)NN * HID_DIM * 4;  // 20.48 MB
    char* p = (char*)d_ws;
    char* slot0 = p;             // Xagg f16 -> H1agg f16 -> g3 f32
    char* slot1 = p + SLOT;      // g1 f32 -> h2 f16
    char* q = p + 2 * SLOT;
    u16* W1Th = (u16*)q; q += (size_t)IN_DIM  * HID_DIM * 2;
    u16* W1Tl = (u16*)q; q += (size_t)IN_DIM  * HID_DIM * 2;
    u16* W2Th = (u16*)q; q += (size_t)HID_DIM * HID_DIM * 2;
    u16* W2Tl = (u16*)q; q += (size_t)HID_DIM * HID_DIM * 2;
    u16* W3Th = (u16*)q; q += (size_t)HID_DIM * OUT_DIM * 2;
    u16* W3Tl = (u16*)q; q += (size_t)HID_DIM * OUT_DIM * 2;
    int*   deg  = (int*)q;   q += (size_t)NN * 4;
    float* dinv = (float*)q; q += (size_t)NN * 4;
    int*   row  = (int*)q;   q += (size_t)NN * 4;
    int*   csr  = (int*)q;   q += (size_t)(NE + NN) * 4;

    u16* Xagg   = (u16*)slot0;                   // f16 [NN][256]
    float* g1   = (float*)slot1;                 // f32, dinv-prescaled
    u16* H1agg  = (u16*)slot0;                   // f16 [NN][512]
    u16* h2     = (u16*)slot1;                   // f16 [NN][512]
    float* g3   = (float*)slot0;                 // f32, dinv-prescaled

    const int T = 256;
    const int MT = (NN + 127) / 128;   // 79
    const int MT8 = (MT + 7) / 8;      // 10

    // ---- init (wsplit + deg zero) + CSR build ----
    {
        int total = IN_DIM * HID_DIM + HID_DIM * HID_DIM + HID_DIM * OUT_DIM + NN;
        k_init<<<(total + T - 1) / T, T, 0, stream>>>(W1, W2, W3, W1Th, W1Tl,
                                                      W2Th, W2Tl, W3Th, W3Tl, deg);
    }
    k_count_deg<<<(NE + T - 1) / T, T, 0, stream>>>(dst, deg);
    k_scan<<<1, 1024, 0, stream>>>(deg, row, csr, dinv);
    k_fill<<<(NE + T - 1) / T, T, 0, stream>>>(src, dst, row, csr);

    const int G256 = ((NN + 31) / 32) * 8;
    const int G512 = ((NN + 15) / 16) * 8;
    const int GEMM_G512 = 8 * MT8 * (HID_DIM / 64);  // 640
    const int GEMM_G256 = 8 * MT8 * (OUT_DIM / 64);  // 320

    // ---- layer 1: Xagg = S*x (f16); g1 = tanh(Xagg@W1+b1)*dinv (f32) ----
    k_gather<false, false, true, IN_DIM / 4><<<G256, 256, 0, stream>>>(
        x, dinv, row, csr, nullptr, nullptr, Xagg);
    k_gemm_f16x2<IN_DIM, true, true, false, true><<<GEMM_G512, 256, 0, stream>>>(
        Xagg, W1Th, W1Tl, b1, dinv, g1, nullptr, NN, HID_DIM, MT, MT8);

    // ---- layer 2: H1agg = S*g1 (f16); h2 = tanh(H1agg@W2+b2) (f16) ----
    k_gather<true, false, true, HID_DIM / 4><<<G512, 256, 0, stream>>>(
        g1, dinv, row, csr, nullptr, nullptr, H1agg);
    k_gemm_f16x2<HID_DIM, true, true, true, false><<<GEMM_G512, 256, 0, stream>>>(
        H1agg, W2Th, W2Tl, b2, nullptr, nullptr, h2, NN, HID_DIM, MT, MT8);

    // ---- layer 3: g3 = (h2@W3)*dinv (f32); out = S*g3 + b3 ----
    k_gemm_f16x2<HID_DIM, false, false, false, true><<<GEMM_G256, 256, 0, stream>>>(
        h2, W3Th, W3Tl, nullptr, dinv, g3, nullptr, NN, OUT_DIM, MT, MT8);
    k_gather<true, true, false, OUT_DIM / 4><<<G256, 256, 0, stream>>>(
        g3, dinv, row, csr, b3, out, nullptr);

    (void)in_sizes; (void)n_in; (void)out_size; (void)ws_size;
}

// Round 11
// 224.957 us; speedup vs baseline: 1.5068x; 1.0500x over previous
//
#include <hip/hip_runtime.h>
#include <math.h>

#define NN 10000
#define NE 160000
#define IN_DIM 256
#define HID_DIM 512
#define OUT_DIM 256

typedef unsigned short u16;
typedef _Float16 f16x8 __attribute__((ext_vector_type(8)));
typedef __attribute__((ext_vector_type(4))) float f32x4;

// ---------------- f16 helpers ----------------

union F16U { _Float16 h; u16 u; };
static __device__ __forceinline__ u16 f2h_bits(float f) {
    F16U v; v.h = (_Float16)f; return v.u;
}

// ---------------- fused init: weight split + x->f16 + deg zero ----------------
// W[K][N] f32 -> T_hi[N][K] f16, T_lo[N][K] f16 scaled 2048 (denormal-proof).
// x[NN][IN_DIM] f32 -> xh f16 (halves gather-1 fetch).

__global__ void k_init(const float* __restrict__ W1, const float* __restrict__ W2,
                       const float* __restrict__ W3, const float* __restrict__ x,
                       u16* __restrict__ W1h, u16* __restrict__ W1l,
                       u16* __restrict__ W2h, u16* __restrict__ W2l,
                       u16* __restrict__ W3h, u16* __restrict__ W3l,
                       u16* __restrict__ xh, int* __restrict__ deg) {
    int idx = blockIdx.x * blockDim.x + threadIdx.x;
    const int S1 = IN_DIM * HID_DIM;
    const int S2 = HID_DIM * HID_DIM;
    const int S3 = HID_DIM * OUT_DIM;
    const int TW = S1 + S2 + S3;
    const int TX = NN * IN_DIM;
    if (idx < TW) {
        const float* W; u16 *Th, *Tl; int K, N, local;
        if (idx < S1)           { W = W1; Th = W1h; Tl = W1l; K = IN_DIM;  N = HID_DIM; local = idx; }
        else if (idx < S1 + S2) { W = W2; Th = W2h; Tl = W2l; K = HID_DIM; N = HID_DIM; local = idx - S1; }
        else                    { W = W3; Th = W3h; Tl = W3l; K = HID_DIM; N = OUT_DIM; local = idx - S1 - S2; }
        int k = local / N, n = local - k * N;
        float v = W[local];
        F16U hh; hh.h = (_Float16)v;
        float r = (v - (float)hh.h) * 2048.0f;
        Th[(size_t)n * K + k] = hh.u;
        Tl[(size_t)n * K + k] = f2h_bits(r);
    } else if (idx < TW + TX) {
        int j = idx - TW;
        xh[j] = f2h_bits(x[j]);
    } else if (idx < TW + TX + NN) {
        deg[idx - TW - TX] = 0;
    }
}

// ---------------- degree / CSR build (self-loops included) ----------------

__global__ void k_count_deg(const int* __restrict__ dst, int* __restrict__ deg) {
    int e = blockIdx.x * blockDim.x + threadIdx.x;
    if (e < NE) atomicAdd(&deg[dst[e]], 1);
}

__launch_bounds__(1024)
__global__ void k_scan(const int* __restrict__ deg, int* __restrict__ row,
                       int* __restrict__ csr, float* __restrict__ dinv) {
    __shared__ int sdeg[10240];
    __shared__ int sums[1024];
    const int tid = threadIdx.x;
    for (int i = tid; i < NN; i += 1024) sdeg[i] = deg[i];
    __syncthreads();
    const int CH = 10;
    int base = tid * CH;
    int s = 0;
    for (int j = 0; j < CH; ++j) {
        int i = base + j;
        if (i < NN) s += sdeg[i] + 1;
    }
    sums[tid] = s;
    __syncthreads();
    for (int off = 1; off < 1024; off <<= 1) {
        int t = (tid >= off) ? sums[tid - off] : 0;
        __syncthreads();
        sums[tid] += t;
        __syncthreads();
    }
    int run = sums[tid] - s;
    for (int j = 0; j < CH; ++j) {
        int i = base + j;
        if (i < NN) {
            int dg = sdeg[i];
            csr[run] = i;        // self entry at slot 0
            row[i] = run + 1;    // fill cursor
            dinv[i] = rsqrtf((float)dg + 1.0f);
            run += dg + 1;
        }
    }
}

__global__ void k_fill(const int* __restrict__ src, const int* __restrict__ dst,
                       int* __restrict__ row, int* __restrict__ csr) {
    int e = blockIdx.x * blockDim.x + threadIdx.x;
    if (e < NE) {
        int pos = atomicAdd(&row[dst[e]], 1);
        csr[pos] = src[e];
    }
}

// ---------------- f16 one-sided-split MFMA GEMM ----------------
// C[M,N] = A[M,K] @ B[K,N]; A single f16 [M][K]; B f16 hi + scaled-lo [N][K].
// acc = A*Bh (accH) + A*(Blo*2048) (accL); result = accH + accL/2048.
// XCD-pinned m-slices, coalesced staging -> fragment-order LDS chunks,
// double-buffered LDS, depth-1 VGPR prefetch, one barrier/iter.

struct PfSet { uint4 a0, a1, bh, bl; };

template<int K, bool HAS_BIAS, bool DO_TANH, bool F16_OUT, bool ROWSCALE>
__launch_bounds__(256)
__global__ void k_gemm_f16x2(const u16* __restrict__ A, const u16* __restrict__ Bhi,
                             const u16* __restrict__ Blo,
                             const float* __restrict__ bias, const float* __restrict__ rowscale,
                             float* __restrict__ C, u16* __restrict__ Ch,
                             int M, int N, int MT, int MT8) {
    __shared__ uint4 As[2][512];   // chunk=(row>>4)*64+kq*16+(row&15)
    __shared__ uint4 BsH[2][256];
    __shared__ uint4 BsL[2][256];

    const int id = blockIdx.x;
    const int xcd = id & 7;
    const int q2 = id >> 3;
    const int mt = (q2 % MT8) * 8 + xcd;
    const int nt = q2 / MT8;
    if (mt >= MT) return;

    const int tid  = threadIdx.x;
    const int wave = tid >> 6;
    const int lane = tid & 63;
    const int lr   = lane & 15;
    const int quad = lane >> 4;
    const int m_base = mt * 128;
    const int n_base = nt * 64;

    const int s_row = tid >> 2;
    const int s_kq  = tid & 3;
    const int c_lo  = ((s_row >> 4) << 6) + s_kq * 16 + (s_row & 15);

    const u16* pA0 = A   + (size_t)(m_base + s_row) * K + s_kq * 8;
    const u16* pA1 = pA0 + (size_t)64 * K;
    const u16* pBh = Bhi + (size_t)(n_base + s_row) * K + s_kq * 8;
    const u16* pBl = Blo + (size_t)(n_base + s_row) * K + s_kq * 8;
    const bool g0 = (m_base + s_row) < M;
    const bool g1 = (m_base + s_row + 64) < M;

    const uint4 z = make_uint4(0u, 0u, 0u, 0u);

    auto load_set = [&](int it, PfSet& r) {
        const int ko = it * 32;
        r.a0 = z; r.a1 = z;
        if (g0) r.a0 = *(const uint4*)(pA0 + ko);
        if (g1) r.a1 = *(const uint4*)(pA1 + ko);
        r.bh = *(const uint4*)(pBh + ko);
        r.bl = *(const uint4*)(pBl + ko);
    };
    auto lds_write = [&](int buf, const PfSet& r) {
        As[buf][c_lo] = r.a0;
        As[buf][c_lo + 256] = r.a1;
        BsH[buf][c_lo] = r.bh;
        BsL[buf][c_lo] = r.bl;
    };

    f32x4 accH[2][4] = {};
    f32x4 accL[2][4] = {};

    auto compute = [&](int buf) {
        f16x8 a[2], bH[4], bL[4];
#pragma unroll
        for (int tm = 0; tm < 2; ++tm) {
            int c = (wave * 2 + tm) * 64 + lane;
            a[tm] = *(const f16x8*)&As[buf][c];
        }
#pragma unroll
        for (int tn = 0; tn < 4; ++tn) {
            int c = tn * 64 + lane;
            bH[tn] = *(const f16x8*)&BsH[buf][c];
            bL[tn] = *(const f16x8*)&BsL[buf][c];
        }
#pragma unroll
        for (int tm = 0; tm < 2; ++tm)
#pragma unroll
            for (int tn = 0; tn < 4; ++tn) {
                accH[tm][tn] = __builtin_amdgcn_mfma_f32_16x16x32_f16(a[tm], bH[tn], accH[tm][tn], 0, 0, 0);
                accL[tm][tn] = __builtin_amdgcn_mfma_f32_16x16x32_f16(a[tm], bL[tn], accL[tm][tn], 0, 0, 0);
            }
    };

    const int NIT = K >> 5;
    PfSet sA;

    load_set(0, sA);
    lds_write(0, sA);
    __syncthreads();

    for (int it = 0; it < NIT; ++it) {
        const bool has_next = (it + 1) < NIT;
        PfSet sN;
        if (has_next) load_set(it + 1, sN);
        compute(it & 1);
        if (has_next) lds_write((it + 1) & 1, sN);
        __syncthreads();
    }

    // epilogue: C/D layout col=lane&15, row=quad*4+i
#pragma unroll
    for (int tm = 0; tm < 2; ++tm) {
        int row0 = m_base + wave * 32 + tm * 16 + quad * 4;
#pragma unroll
        for (int i = 0; i < 4; ++i) {
            int row = row0 + i;
            if (row >= M) continue;
            float rs = ROWSCALE ? rowscale[row] : 1.0f;
#pragma unroll
            for (int tn = 0; tn < 4; ++tn) {
                int col = n_base + tn * 16 + lr;
                float v = accH[tm][tn][i] + accL[tm][tn][i] * (1.0f / 2048.0f);
                if (HAS_BIAS) v += bias[col];
                if (DO_TANH) v = tanhf(v);
                if (ROWSCALE) v *= rs;
                if (F16_OUT) {
                    Ch[(size_t)row * N + col] = f2h_bits(v);
                } else {
                    C[(size_t)row * N + col] = v;
                }
            }
        }
    }
}

// ---------------- XCD-sliced fused gather aggregation, f16 input ----------------
// res[d] = dd * sum_{s in csr(d)} w(s)*h[s] (+bias); self-loop in csr.
// h is f16 [NN][F]; each lane owns 8 features (16 B load). 8 XCD feature
// slices (block%8). F16_OUT: write 8 f16 (GEMM A row); else 8 f32 (+bias).

template<bool PRESCALED, bool HAS_BIAS, bool F16_OUT, int F>
__launch_bounds__(256)
__global__ void k_gather_h(const u16* __restrict__ h, const float* __restrict__ dinv,
                           const int* __restrict__ row_end, const int* __restrict__ csr,
                           const float* __restrict__ bias,
                           float* __restrict__ outF, u16* __restrict__ outH) {
    constexpr int L  = F / 8;    // 16B lanes per node row
    constexpr int LS = L / 8;    // lanes per node per slice
    constexpr int NPB = 256 / LS;
    const int tid = threadIdx.x;
    const int d = (blockIdx.x >> 3) * NPB + tid / LS;
    if (d >= NN) return;
    const int f8 = (blockIdx.x & 7) * LS + (tid & (LS - 1));  // 8-feature chunk idx

    const int start = (d == 0) ? 0 : row_end[d - 1];
    const int end = row_end[d];
    const uint4* h16 = (const uint4*)h;

    float acc[8] = {};
    int e = start;
    for (; e + 8 <= end; e += 8) {
        int s[8]; uint4 raw[8]; float w[8];
#pragma unroll
        for (int j = 0; j < 8; ++j) s[j] = csr[e + j];
#pragma unroll
        for (int j = 0; j < 8; ++j) raw[j] = h16[(size_t)s[j] * L + f8];
#pragma unroll
        for (int j = 0; j < 8; ++j) w[j] = PRESCALED ? 1.0f : dinv[s[j]];
#pragma unroll
        for (int j = 0; j < 8; ++j) {
            f16x8 hv = *(const f16x8*)&raw[j];
#pragma unroll
            for (int t = 0; t < 8; ++t) acc[t] += w[j] * (float)hv[t];
        }
    }
    for (; e < end; ++e) {
        int s = csr[e];
        float w = PRESCALED ? 1.0f : dinv[s];
        uint4 raw = h16[(size_t)s * L + f8];
        f16x8 hv = *(const f16x8*)&raw;
#pragma unroll
        for (int t = 0; t < 8; ++t) acc[t] += w * (float)hv[t];
    }

    const float dd = dinv[d];
    float r[8];
#pragma unroll
    for (int t = 0; t < 8; ++t) r[t] = dd * acc[t];
    if (HAS_BIAS) {
        const float4* b4 = (const float4*)bias;
        float4 b0 = b4[f8 * 2], b1 = b4[f8 * 2 + 1];
        r[0] += b0.x; r[1] += b0.y; r[2] += b0.z; r[3] += b0.w;
        r[4] += b1.x; r[5] += b1.y; r[6] += b1.z; r[7] += b1.w;
    }
    if (F16_OUT) {
        union { u16 a[8]; uint4 v; } pk;
#pragma unroll
        for (int t = 0; t < 8; ++t) pk.a[t] = f2h_bits(r[t]);
        ((uint4*)outH)[(size_t)d * L + f8] = pk.v;
    } else {
        size_t base = (size_t)d * (F / 4) + f8 * 2;
        ((float4*)outF)[base]     = make_float4(r[0], r[1], r[2], r[3]);
        ((float4*)outF)[base + 1] = make_float4(r[4], r[5], r[6], r[7]);
    }
}

// ---------------- launch ----------------

extern "C" void kernel_launch(void* const* d_in, const int* in_sizes, int n_in,
                              void* d_out, int out_size, void* d_ws, size_t ws_size,
                              hipStream_t stream) {
    const float* x  = (const float*)d_in[0];
    const float* W1 = (const float*)d_in[1];
    const float* b1 = (const float*)d_in[2];
    const float* W2 = (const float*)d_in[3];
    const float* b2 = (const float*)d_in[4];
    const float* W3 = (const float*)d_in[5];
    const float* b3 = (const float*)d_in[6];
    const int* edge = (const int*)d_in[7];
    const int* src = edge;
    const int* dst = edge + NE;
    float* out = (float*)d_out;

    const size_t SLOT = (size_t)NN * HID_DIM * 4;  // 20.48 MB
    char* p = (char*)d_ws;
    char* slot0 = p;             // Xagg f16 -> H1agg f16 -> g3 f16
    char* slot1 = p + SLOT;      // g1 f16 -> h2 f16
    char* q = p + 2 * SLOT;
    u16* W1Th = (u16*)q; q += (size_t)IN_DIM  * HID_DIM * 2;
    u16* W1Tl = (u16*)q; q += (size_t)IN_DIM  * HID_DIM * 2;
    u16* W2Th = (u16*)q; q += (size_t)HID_DIM * HID_DIM * 2;
    u16* W2Tl = (u16*)q; q += (size_t)HID_DIM * HID_DIM * 2;
    u16* W3Th = (u16*)q; q += (size_t)HID_DIM * OUT_DIM * 2;
    u16* W3Tl = (u16*)q; q += (size_t)HID_DIM * OUT_DIM * 2;
    int*   deg  = (int*)q;   q += (size_t)NN * 4;
    float* dinv = (float*)q; q += (size_t)NN * 4;
    int*   row  = (int*)q;   q += (size_t)NN * 4;
    int*   csr  = (int*)q;   q += (size_t)(NE + NN) * 4;
    u16*   xh   = (u16*)q;   q += (size_t)NN * IN_DIM * 2;

    u16* Xagg  = (u16*)slot0;   // f16 [NN][256]
    u16* g1h   = (u16*)slot1;   // f16 [NN][512], dinv-prescaled
    u16* H1agg = (u16*)slot0;   // f16 [NN][512]
    u16* h2    = (u16*)slot1;   // f16 [NN][512]
    u16* g3h   = (u16*)slot0;   // f16 [NN][256], dinv-prescaled

    const int T = 256;
    const int MT = (NN + 127) / 128;   // 79
    const int MT8 = (MT + 7) / 8;      // 10

    // ---- init (wsplit + x->f16 + deg zero) + CSR build ----
    {
        int total = IN_DIM * HID_DIM + HID_DIM * HID_DIM + HID_DIM * OUT_DIM
                  + NN * IN_DIM + NN;
        k_init<<<(total + T - 1) / T, T, 0, stream>>>(W1, W2, W3, x, W1Th, W1Tl,
                                                      W2Th, W2Tl, W3Th, W3Tl, xh, deg);
    }
    k_count_deg<<<(NE + T - 1) / T, T, 0, stream>>>(dst, deg);
    k_scan<<<1, 1024, 0, stream>>>(deg, row, csr, dinv);
    k_fill<<<(NE + T - 1) / T, T, 0, stream>>>(src, dst, row, csr);

    // gather grids: 8 slices x node groups
    const int G256 = ((NN + 63) / 64) * 8;   // F=256: NPB=64 -> 1256
    const int G512 = ((NN + 31) / 32) * 8;   // F=512: NPB=32 -> 2504
    const int GEMM_G512 = 8 * MT8 * (HID_DIM / 64);  // 640
    const int GEMM_G256 = 8 * MT8 * (OUT_DIM / 64);  // 320

    // ---- layer 1: Xagg = S*xh (f16); g1 = tanh(Xagg@W1+b1)*dinv (f16) ----
    k_gather_h<false, false, true, IN_DIM><<<G256, 256, 0, stream>>>(
        xh, dinv, row, csr, nullptr, nullptr, Xagg);
    k_gemm_f16x2<IN_DIM, true, true, true, true><<<GEMM_G512, 256, 0, stream>>>(
        Xagg, W1Th, W1Tl, b1, dinv, nullptr, g1h, NN, HID_DIM, MT, MT8);

    // ---- layer 2: H1agg = S*g1 (f16); h2 = tanh(H1agg@W2+b2) (f16) ----
    k_gather_h<true, false, true, HID_DIM><<<G512, 256, 0, stream>>>(
        g1h, dinv, row, csr, nullptr, nullptr, H1agg);
    k_gemm_f16x2<HID_DIM, true, true, true, false><<<GEMM_G512, 256, 0, stream>>>(
        H1agg, W2Th, W2Tl, b2, nullptr, nullptr, h2, NN, HID_DIM, MT, MT8);

    // ---- layer 3: g3 = (h2@W3)*dinv (f16); out = S*g3 + b3 (f32) ----
    k_gemm_f16x2<HID_DIM, false, false, true, true><<<GEMM_G256, 256, 0, stream>>>(
        h2, W3Th, W3Tl, nullptr, dinv, nullptr, g3h, NN, OUT_DIM, MT, MT8);
    k_gather_h<true, true, false, OUT_DIM><<<G256, 256, 0, stream>>>(
        g3h, dinv, row, csr, b3, out, nullptr);

    (void)in_sizes; (void)n_in; (void)out_size; (void)ws_size;
}